// Round 7
// baseline (3364.666 us; speedup 1.0000x reference)
//
#include <hip/hip_runtime.h>

#define B_ 64
#define T_ 2048
#define F_ 8
#define H_ 128
#define RING_LD 68   // 64 dwords + 4 pad for the OUT burst reads

typedef _Float16 v2h  __attribute__((ext_vector_type(2)));
typedef _Float16 f16x8 __attribute__((ext_vector_type(8)));
typedef float    f32x4 __attribute__((ext_vector_type(4)));

// pack two fp32 into one dword of two f16
__device__ __forceinline__ unsigned pk2h(float lo, float hi) {
    v2h p;
    p[0] = (_Float16)lo;
    p[1] = (_Float16)hi;
    return __builtin_bit_cast(unsigned, p);
}

#if __has_builtin(__builtin_amdgcn_fdot2)
__device__ __forceinline__ float fdot2a(unsigned a, unsigned b, float c) {
    return __builtin_amdgcn_fdot2(__builtin_bit_cast(v2h, a),
                                  __builtin_bit_cast(v2h, b), c, false);
}
#else
__device__ __forceinline__ float fdot2a(unsigned a, unsigned b, float c) {
    v2h av = __builtin_bit_cast(v2h, a);
    v2h bv = __builtin_bit_cast(v2h, b);
    c += (float)av[0] * (float)bv[0];
    c += (float)av[1] * (float)bv[1];
    return c;
}
#endif

__device__ __forceinline__ float sigm(float x) {
    return 1.0f / (1.0f + __expf(-x));
}
__device__ __forceinline__ float tanh_f(float x) {
    float e = __expf(2.0f * x);
    return 1.0f - 2.0f / (e + 1.0f);
}

__device__ __forceinline__ f32x4 mfma16(f16x8 a, f16x8 b, f32x4 c) {
    return __builtin_amdgcn_mfma_f32_16x16x32_f16(a, b, c, 0, 0, 0);
}

// ---------------------------------------------------------------------------
// MFMA formulation. Per block = 1 batch element, 512 threads = 8 waves.
// Wave w owns h indices [w*16, w*16+16); within it, lane column n = l&15.
// Gate matvec gates = W[512x128] * h[128] is computed as D = A*B with
//   A[m][k] = h[k]  (all 16 rows identical -> D row-replicated),
//   B[k][n] = W[j*128 + w*16 + n][k]   (tile j = gate j in PyTorch i,f,g,o order)
// Both A and B fragments are filled with the SAME k-enumeration
// k ~ (grp = l>>4, elem j): f(grp,j) = grp*8 + j. Because the dot sums over k,
// any consistent bijection is correct regardless of the HW's internal k map.
// D layout (HW-verified, dtype-independent): col = lane&15 -> lane l ends up
// holding gate j of h_idx (w*16 + (l&15)) for all four tiles j => the entire
// LSTM cell update is per-lane straight-line code, no lane exchanges.
// Weights live in AGPRs as MFMA B-operands (MFMA reads AGPRs natively ->
// the v_accvgpr_read tax that capped all fdot2 variants at ~3.2 ms is gone).
// ---------------------------------------------------------------------------
__global__ __launch_bounds__(512)
__attribute__((amdgpu_waves_per_eu(2, 2)))
void lstm2_mfma_kernel(const float* __restrict__ x,
                       const float* __restrict__ wih0,
                       const float* __restrict__ whh0,
                       const float* __restrict__ bih0,
                       const float* __restrict__ bhh0,
                       const float* __restrict__ wih1,
                       const float* __restrict__ whh1,
                       const float* __restrict__ bih1,
                       const float* __restrict__ bhh1,
                       const float* __restrict__ wlin,
                       const float* __restrict__ blin,
                       float* __restrict__ out)
{
    __shared__ __align__(16) unsigned x_lds[T_ * F_ / 2];     // 32 KB packed f16 x
    __shared__ __align__(16) unsigned h0_lds[2][H_ / 2];      // double-buffered h0 (f16)
    __shared__ __align__(16) unsigned h1_lds[2][H_ / 2];      // double-buffered h1 (f16)
    __shared__ __align__(16) unsigned h1_ring[64 * RING_LD];  // 64-tick h1 ring (17 KB)
    __shared__ __align__(16) unsigned wlin_p[F_ * RING_LD];   // w_lin rows, padded
    __shared__ __align__(16) uint4    wih0_f[8 * 4 * 64];     // Wih0 B-frags (32 KB)
    __shared__ float blin_f[F_];

    const int tid = threadIdx.x;
    const int b   = blockIdx.x;
    const int w   = tid >> 6;     // wave 0..7
    const int l   = tid & 63;     // lane
    const int n   = l & 15;       // fragment column == h_idx offset
    const int grp = l >> 4;       // k-slice group 0..3

    // ---- stage x[b] into LDS as packed f16 pairs ----
    const float4* xp = (const float4*)(x + (size_t)b * T_ * F_);
    #pragma unroll
    for (int i = 0; i < 8; ++i) {
        int idx = tid + i * 512;          // 4096 float4 total
        float4 v = xp[idx];
        x_lds[idx * 2 + 0] = pk2h(v.x, v.y);
        x_lds[idx * 2 + 1] = pk2h(v.z, v.w);
    }

    // ---- Wih0 B-frags -> LDS (K=8 padded to 32; only grp==0 lanes nonzero) ----
    #pragma unroll
    for (int j = 0; j < 4; ++j) {
        f16x8 wf = {};
        if (grp == 0) {
            const float* p = wih0 + (size_t)(j * H_ + w * 16 + n) * F_;
            #pragma unroll
            for (int jj = 0; jj < 8; ++jj) wf[jj] = (_Float16)p[jj];
        }
        wih0_f[(w * 4 + j) * 64 + l] = __builtin_bit_cast(uint4, wf);
    }

    // ---- big weight matrices as B-frags in registers (AGPR-resident) ----
    // frag [j][s]: elem jj = W[j*128 + w*16 + n][s*32 + grp*8 + jj]
    f16x8 wf_hh0[4][4], wf_ih1[4][4], wf_hh1[4][4];
    #pragma unroll
    for (int j = 0; j < 4; ++j) {
        const int row = j * H_ + w * 16 + n;
        #pragma unroll
        for (int s = 0; s < 4; ++s) {
            const float* p0 = whh0 + (size_t)row * H_ + s * 32 + grp * 8;
            const float* p1 = wih1 + (size_t)row * H_ + s * 32 + grp * 8;
            const float* p2 = whh1 + (size_t)row * H_ + s * 32 + grp * 8;
            f16x8 f0, f1, f2;
            #pragma unroll
            for (int jj = 0; jj < 8; ++jj) {
                f0[jj] = (_Float16)p0[jj];
                f1[jj] = (_Float16)p1[jj];
                f2[jj] = (_Float16)p2[jj];
            }
            wf_hh0[j][s] = f0;
            wf_ih1[j][s] = f1;
            wf_hh1[j][s] = f2;
        }
    }

    // biases for this lane's 4 gates (gate j of h_idx w*16+n)
    float bb0[4], bb1[4];
    #pragma unroll
    for (int j = 0; j < 4; ++j) {
        const int row = j * H_ + w * 16 + n;
        bb0[j] = bih0[row] + bhh0[row];
        bb1[j] = bih1[row] + bhh1[row];
    }

    // w_lin: [8][128] fp32 -> padded rows of 64 packed pairs (for OUT burst)
    {
        int r = tid >> 6, c = tid & 63;
        float2 v = ((const float2*)wlin)[r * 64 + c];
        wlin_p[r * RING_LD + c] = pk2h(v.x, v.y);
    }
    if (tid < F_) blin_f[tid] = blin[tid];
    if (tid < H_ / 2) {
        h0_lds[0][tid] = 0u; h0_lds[1][tid] = 0u;
        h1_lds[0][tid] = 0u; h1_lds[1][tid] = 0u;
    }
    __syncthreads();

    float c0 = 0.0f, c1 = 0.0f;   // cell state (replicated across the 4 grp copies)

    for (int t = 0; t < T_; ++t) {
        const int rp = (t + 1) & 1;   // parity holding state(t-1)
        const int wp = t & 1;         // parity receiving state(t)

        // ---------- phase 1: layer 0 ----------
        {
            f32x4 a0 = {}, a1 = {}, a2 = {}, a3 = {};
            #pragma unroll
            for (int s = 0; s < 4; ++s) {
                uint4 hv = *(const uint4*)&h0_lds[rp][s * 16 + grp * 4];
                f16x8 ah = __builtin_bit_cast(f16x8, hv);
                a0 = mfma16(ah, wf_hh0[0][s], a0);
                a1 = mfma16(ah, wf_hh0[1][s], a1);
                a2 = mfma16(ah, wf_hh0[2][s], a2);
                a3 = mfma16(ah, wf_hh0[3][s], a3);
            }
            // x contribution: A = x padded to K=32 (grp>0 lanes carry zeros)
            {
                uint4 xv = *(const uint4*)&x_lds[t * 4];
                f16x8 ax = __builtin_bit_cast(f16x8, xv);
                if (grp != 0) ax = (f16x8){};
                a0 = mfma16(ax, __builtin_bit_cast(f16x8, wih0_f[(w * 4 + 0) * 64 + l]), a0);
                a1 = mfma16(ax, __builtin_bit_cast(f16x8, wih0_f[(w * 4 + 1) * 64 + l]), a1);
                a2 = mfma16(ax, __builtin_bit_cast(f16x8, wih0_f[(w * 4 + 2) * 64 + l]), a2);
                a3 = mfma16(ax, __builtin_bit_cast(f16x8, wih0_f[(w * 4 + 3) * 64 + l]), a3);
            }
            // D is row-replicated -> reg 0 holds this lane's gate value
            float gi = sigm(a0[0] + bb0[0]);
            float gf = sigm(a1[0] + bb0[1]);
            float gg = tanh_f(a2[0] + bb0[2]);
            float go = sigm(a3[0] + bb0[3]);
            c0 = gf * c0 + gi * gg;
            float hv0 = go * tanh_f(c0);
            if (l < 16) ((_Float16*)&h0_lds[wp][0])[w * 16 + l] = (_Float16)hv0;
        }

        __syncthreads();   // h0(t) visible

        // ---------- phase 2: layer 1 ----------
        {
            f32x4 a0 = {}, a1 = {}, a2 = {}, a3 = {};
            #pragma unroll
            for (int s = 0; s < 4; ++s) {
                uint4 hv = *(const uint4*)&h0_lds[wp][s * 16 + grp * 4];   // h0(t)
                f16x8 ah = __builtin_bit_cast(f16x8, hv);
                a0 = mfma16(ah, wf_ih1[0][s], a0);
                a1 = mfma16(ah, wf_ih1[1][s], a1);
                a2 = mfma16(ah, wf_ih1[2][s], a2);
                a3 = mfma16(ah, wf_ih1[3][s], a3);
            }
            #pragma unroll
            for (int s = 0; s < 4; ++s) {
                uint4 hv = *(const uint4*)&h1_lds[rp][s * 16 + grp * 4];   // h1(t-1)
                f16x8 ah = __builtin_bit_cast(f16x8, hv);
                a0 = mfma16(ah, wf_hh1[0][s], a0);
                a1 = mfma16(ah, wf_hh1[1][s], a1);
                a2 = mfma16(ah, wf_hh1[2][s], a2);
                a3 = mfma16(ah, wf_hh1[3][s], a3);
            }
            float gi = sigm(a0[0] + bb1[0]);
            float gf = sigm(a1[0] + bb1[1]);
            float gg = tanh_f(a2[0] + bb1[2]);
            float go = sigm(a3[0] + bb1[3]);
            c1 = gf * c1 + gi * gg;
            float hv1 = go * tanh_f(c1);
            if (l < 16) {
                _Float16 hh = (_Float16)hv1;
                ((_Float16*)&h1_lds[wp][0])[w * 16 + l] = hh;
                ((_Float16*)h1_ring)[(t & 63) * (RING_LD * 2) + w * 16 + l] = hh;
            }
        }

        __syncthreads();   // h1(t) + ring slot visible

        // ---------- OUT burst: every 64 ticks, 512 outputs in parallel ----------
        if ((t & 63) == 63) {
            const int tick_i = tid >> 3;   // ring slot == tick (t-63+tick_i)
            const int fo     = tid & 7;    // output feature
            const unsigned* hp = &h1_ring[tick_i * RING_LD];
            const unsigned* wv = &wlin_p[fo * RING_LD];
            float a = 0.0f;
            #pragma unroll
            for (int j = 0; j < 16; ++j) {
                uint4 hv = *(const uint4*)&hp[j * 4];
                uint4 wq = *(const uint4*)&wv[j * 4];
                a = fdot2a(wq.x, hv.x, a);
                a = fdot2a(wq.y, hv.y, a);
                a = fdot2a(wq.z, hv.z, a);
                a = fdot2a(wq.w, hv.w, a);
            }
            out[(size_t)b * T_ * F_ + (size_t)(t - 63) * F_ + tid] = a + blin_f[fo];
            // store drains at the next phase-1 barrier (once per 64 ticks)
        }
    }
}

extern "C" void kernel_launch(void* const* d_in, const int* in_sizes, int n_in,
                              void* d_out, int out_size, void* d_ws, size_t ws_size,
                              hipStream_t stream) {
    const float* x    = (const float*)d_in[0];
    const float* wih0 = (const float*)d_in[1];
    const float* whh0 = (const float*)d_in[2];
    const float* bih0 = (const float*)d_in[3];
    const float* bhh0 = (const float*)d_in[4];
    const float* wih1 = (const float*)d_in[5];
    const float* whh1 = (const float*)d_in[6];
    const float* bih1 = (const float*)d_in[7];
    const float* bhh1 = (const float*)d_in[8];
    const float* wlin = (const float*)d_in[9];
    const float* blin = (const float*)d_in[10];
    float* out = (float*)d_out;

    lstm2_mfma_kernel<<<dim3(B_), dim3(512), 0, stream>>>(
        x, wih0, whh0, bih0, bhh0, wih1, whh1, bih1, bhh1, wlin, blin, out);
}